// Round 1
// baseline (172.715 us; speedup 1.0000x reference)
//
#include <hip/hip_runtime.h>
#include <math.h>

// Problem constants (from reference): B=2, HD=4, H=W=128, KSIZE=7 (K=49), NSP=9, S=64
#define BN   2
#define HDN  4
#define HN   128
#define WN   128
#define KS   7
#define KK   49
#define NSPN 9
#define SN   64

// One wave (64 lanes) per pixel (b,hh,ww). Lanes 0..48 <-> tap k.
// attn/out accesses are contiguous 49-float runs per wave -> coalesced.
// sims gathers: per sp, 7 rows x 7 contiguous floats (L2/L3 resident, 8 MB total).
__global__ __launch_bounds__(256) void attn_rw_kernel(
    const float* __restrict__ attn,
    const float* __restrict__ sims,
    const int*   __restrict__ sinds,
    float*       __restrict__ out)
{
    const int lane = threadIdx.x & 63;
    const int wid  = threadIdx.x >> 6;
    const int pix  = (blockIdx.x << 2) | wid;      // 0 .. B*H*W-1 = 32767
    const int b    = pix >> 14;                    // / (128*128)
    const int hh   = (pix >> 7) & 127;
    const int ww   = pix & 127;

    const bool valid = lane < KK;
    const int ki = lane / KS;                      // row within 7x7 window
    const int kj = lane - ki * KS;                 // col within 7x7 window

    // neighbor window start: clip(center-3, 0, N-7)
    int hs = hh - (KS / 2); hs = max(0, min(HN - KS, hs));
    int ws = ww - (KS / 2); ws = max(0, min(WN - KS, ws));
    const int hjv = hs + ki;
    const int wjv = ws + kj;

    // ---- attn: load, wave-max, exp (per head) ----
    float a[HDN];
    #pragma unroll
    for (int hd = 0; hd < HDN; ++hd) {
        const int idx = (((b * HDN + hd) * HN + hh) * WN + ww) * KK + lane;
        const float v = valid ? attn[idx] : -3.0e38f;
        float m = v;
        #pragma unroll
        for (int s = 32; s >= 1; s >>= 1)
            m = fmaxf(m, __shfl_xor(m, s));
        a[hd] = valid ? __expf(v - m) : 0.0f;      // invalid lanes contribute 0 to sums
    }

    // ---- superpixel ids + center similarity (lanes 0..8 load, broadcast later) ----
    int   gv  = 0;
    float piv = 0.0f;
    if (lane < NSPN) {
        gv  = sinds[((b * HN + hh) * WN + ww) * NSPN + lane];
        piv = sims[((b * SN + gv) * HN + hh) * WN + ww];
    }

    // ---- main loop over superpixels ----
    float acc[HDN] = {0.0f, 0.0f, 0.0f, 0.0f};
    #pragma unroll
    for (int sp = 0; sp < NSPN; ++sp) {
        const int   g  = __shfl(gv, sp);
        const float pi = __shfl(piv, sp);
        const float p  = valid ? sims[((b * SN + g) * HN + hjv) * WN + wjv] : 0.0f;
        #pragma unroll
        for (int hd = 0; hd < HDN; ++hd) {
            float d = a[hd] * p;                   // lanes >=49 hold 0
            #pragma unroll
            for (int s = 32; s >= 1; s >>= 1)
                d += __shfl_xor(d, s);             // denom = sum_k a*p
            acc[hd] += (pi / (1e-10f + d)) * p;
        }
    }

    // ---- write out[hd,k] = a * sum_sp coef*p ----
    if (valid) {
        #pragma unroll
        for (int hd = 0; hd < HDN; ++hd) {
            const int idx = (((b * HDN + hd) * HN + hh) * WN + ww) * KK + lane;
            out[idx] = a[hd] * acc[hd];
        }
    }
}

extern "C" void kernel_launch(void* const* d_in, const int* in_sizes, int n_in,
                              void* d_out, int out_size, void* d_ws, size_t ws_size,
                              hipStream_t stream) {
    const float* attn  = (const float*)d_in[0];
    const float* sims  = (const float*)d_in[1];
    const int*   sinds = (const int*)d_in[2];
    float*       out   = (float*)d_out;

    // 32768 pixels, 4 waves (pixels) per 256-thread block -> 8192 blocks
    const int nPix   = BN * HN * WN;
    const int blocks = nPix / 4;
    attn_rw_kernel<<<blocks, 256, 0, stream>>>(attn, sims, sinds, out);
}

// Round 2
// 129.264 us; speedup vs baseline: 1.3361x; 1.3361x over previous
//
#include <hip/hip_runtime.h>
#include <math.h>

// B=2, HD=4, H=W=128, KSIZE=7 (K=49), NSP=9, S=64
#define BN   2
#define HDN  4
#define HN   128
#define WN   128
#define KS   7
#define KK   49
#define NSPN 9
#define SN   64
#define PPB  32      // pixels per block
#define TPB  128     // threads per block (32 pix x 4 heads)
#define PROW 52      // padded LDS row stride (floats), 16B-aligned

// Thread (pix, hd) does all K-work serially in registers: no cross-lane
// reductions, no divisions (v_rcp). p-patches gathered wave-per-(pixel,sp)
// (7x7 contiguous rows -> coalesced L2 hits), double-buffered in LDS.
__global__ __launch_bounds__(TPB, 2) void attn_rw2(
    const float* __restrict__ attn,
    const float* __restrict__ sims,
    const int*   __restrict__ sinds,
    float*       __restrict__ out)
{
    __shared__ __align__(16) float pbuf[2][PPB * PROW];
    __shared__ int   g_lds[PPB * NSPN];
    __shared__ float pi_lds[PPB * NSPN];

    const int t    = threadIdx.x;
    const int lane = t & 63;
    const int wv   = t >> 6;                 // wave id 0..1
    const int bx   = blockIdx.x;
    const int wseg = bx & 3;
    const int hh   = (bx >> 2) & 127;
    const int b    = bx >> 9;
    const int ww0  = wseg * PPB;

    const int pix_c = t & 31;                // compute mapping
    const int hd    = t >> 5;

    const float* simsB = sims + ((size_t)b << 20);   // b * 64*128*128
    int hs = hh - 3; hs = max(0, min(HN - KS, hs));  // uniform per block

    // ---- stage sinds (288 contiguous ints) ----
    const int sbase = ((b * HN + hh) * WN + ww0) * NSPN;
    for (int e = t; e < PPB * NSPN; e += TPB)
        g_lds[e] = sinds[sbase + e];
    __syncthreads();

    // ---- stage pi (center similarity per (pix,sp)) ----
    for (int e = t; e < PPB * NSPN; e += TPB) {
        int g   = g_lds[e];
        int pix = e / NSPN;
        pi_lds[e] = simsB[(g << 14) + hh * WN + ww0 + pix];
    }

    // ---- per-thread attn: 49 contiguous loads, tree-max, exp ----
    float a[KK];
    {
        const size_t abase =
            ((((size_t)b * HDN + hd) * HN + hh) * WN + (ww0 + pix_c)) * (size_t)KK;
        #pragma unroll
        for (int k = 0; k < KK; ++k) a[k] = attn[abase + k];
        float m0 = a[0], m1 = a[1], m2 = a[2], m3 = a[3];
        #pragma unroll
        for (int k = 4; k < KK; k += 4) {
            m0 = fmaxf(m0, a[k]);
            if (k + 1 < KK) m1 = fmaxf(m1, a[k + 1]);
            if (k + 2 < KK) m2 = fmaxf(m2, a[k + 2]);
            if (k + 3 < KK) m3 = fmaxf(m3, a[k + 3]);
        }
        float m = fmaxf(fmaxf(m0, m1), fmaxf(m2, m3));
        #pragma unroll
        for (int k = 0; k < KK; ++k) a[k] = __expf(a[k] - m);
    }

    // gather lane constants
    const int  gki     = lane / KS;
    const int  gkj     = lane - gki * KS;
    const int  laneoff = gki * WN + gkj;     // offset inside 7x7 window
    const bool gact    = lane < KK;

    // gather one sp-plane for this block's 32 pixels into pbuf[buf]
    auto gather = [&](int sp, int buf) {
        int gv = 0;
        if (lane < 16)
            gv = g_lds[(wv * 16 + lane) * NSPN + sp];
        #pragma unroll
        for (int i = 0; i < 16; ++i) {
            int g   = __builtin_amdgcn_readlane(gv, i);   // scalar g
            int pix = wv * 16 + i;
            int ws  = ww0 + pix - 3; ws = max(0, min(WN - KS, ws));
            const float* src = simsB + (g << 14) + hs * WN + ws;
            if (gact)
                pbuf[buf][pix * PROW + lane] = src[laneoff];
        }
    };

    gather(0, 0);
    __syncthreads();     // pbuf[0], pi_lds ready

    float acc[KK];
    #pragma unroll
    for (int k = 0; k < KK; ++k) acc[k] = 0.0f;

    for (int sp = 0; sp < NSPN; ++sp) {
        const int buf = sp & 1;
        if (sp + 1 < NSPN) gather(sp + 1, buf ^ 1);   // overlap next gather

        // load p row into regs (12 x b128 + 1)
        float p[KK];
        const float* prow = &pbuf[buf][pix_c * PROW];
        #pragma unroll
        for (int k4 = 0; k4 < 12; ++k4) {
            float4 v = *(const float4*)(prow + k4 * 4);
            p[k4 * 4 + 0] = v.x; p[k4 * 4 + 1] = v.y;
            p[k4 * 4 + 2] = v.z; p[k4 * 4 + 3] = v.w;
        }
        p[48] = prow[48];

        // denom: 4-way split FMA chains
        float d0 = 0.f, d1 = 0.f, d2 = 0.f, d3 = 0.f;
        #pragma unroll
        for (int k = 0; k < 48; k += 4) {
            d0 = fmaf(a[k + 0], p[k + 0], d0);
            d1 = fmaf(a[k + 1], p[k + 1], d1);
            d2 = fmaf(a[k + 2], p[k + 2], d2);
            d3 = fmaf(a[k + 3], p[k + 3], d3);
        }
        d0 = fmaf(a[48], p[48], d0);
        float d  = (d0 + d1) + (d2 + d3);

        float pi   = pi_lds[pix_c * NSPN + sp];
        float coef = pi * __builtin_amdgcn_rcpf(d + 1e-10f);

        #pragma unroll
        for (int k = 0; k < KK; ++k) acc[k] = fmaf(coef, p[k], acc[k]);

        __syncthreads();   // publish gather(sp+1); WAR-protect buf for sp+2
    }

    // ---- epilogue: out[k] = a[k] * acc[k], contiguous 49-run per thread ----
    const size_t obase =
        ((((size_t)b * HDN + hd) * HN + hh) * WN + (ww0 + pix_c)) * (size_t)KK;
    #pragma unroll
    for (int k = 0; k < KK; ++k) out[obase + k] = a[k] * acc[k];
}

extern "C" void kernel_launch(void* const* d_in, const int* in_sizes, int n_in,
                              void* d_out, int out_size, void* d_ws, size_t ws_size,
                              hipStream_t stream) {
    const float* attn  = (const float*)d_in[0];
    const float* sims  = (const float*)d_in[1];
    const int*   sinds = (const int*)d_in[2];
    float*       outp  = (float*)d_out;

    // blocks: b(2) x hh(128) x wseg(4) = 1024
    const int blocks = BN * HN * (WN / PPB);
    attn_rw2<<<blocks, TPB, 0, stream>>>(attn, sims, sinds, outp);
}